// Round 1
// baseline (212.966 us; speedup 1.0000x reference)
//
#include <hip/hip_runtime.h>

// Problem constants (match reference)
constexpr int N    = 8192;     // nodes
constexpr int D    = 128;      // feature dim
constexpr int NE   = 131072;   // edges
constexpr int WPR  = N / 32;   // 256 u32 words per bitset row

// f(k) = exp(-ALPHA*k), ALPHA = 2
#define F1 0.13533528323661270f   // e^-2
#define F2 0.018315638888734179f  // e^-4
#define F3 0.0024787521766663585f // e^-6

// ---------------------------------------------------------------------------
// GEMM: H = relu(X @ W), X [N,128], W [128,128].
// If fuse_final: after relu, dot rows with W3 [128] -> angles[N] (h2 never stored).
// Tile: 32 rows/block, 256 threads, each thread 2 rows x 8 cols.
// LDS: Xs 16KB + Ws 32KB (two k-halves) + w3 0.5KB = 48.5KB -> 3 blocks/CU.
// ---------------------------------------------------------------------------
__global__ __launch_bounds__(256) void gemm_relu(
    const float* __restrict__ X, const float* __restrict__ W,
    float* __restrict__ H, const float* __restrict__ W3,
    float* __restrict__ angles, int fuse_final)
{
    __shared__ float Xs[32 * 128];
    __shared__ float Ws[64 * 128];
    __shared__ float w3s[128];

    const int tid  = threadIdx.x;
    const int row0 = blockIdx.x * 32;

    // stage X tile (32 full rows, contiguous)
    for (int i = tid * 4; i < 32 * 128; i += 256 * 4)
        *(float4*)&Xs[i] = *(const float4*)&X[row0 * 128 + i];
    if (fuse_final && tid < 128) w3s[tid] = W3[tid];

    const int cg = tid & 15;       // 16 col-groups of 8 cols
    const int rp = tid >> 4;       // 16 row-pairs
    const int r0 = rp * 2;
    const int c0 = cg * 8;

    float acc[2][8];
#pragma unroll
    for (int r = 0; r < 2; ++r)
#pragma unroll
        for (int c = 0; c < 8; ++c) acc[r][c] = 0.0f;

    for (int kh = 0; kh < 2; ++kh) {
        __syncthreads();  // previous chunk consumed (also fences Xs stage on kh=0... wait Xs must be ready before compute; the second sync below covers it)
        for (int i = tid * 4; i < 64 * 128; i += 256 * 4)
            *(float4*)&Ws[i] = *(const float4*)&W[kh * 64 * 128 + i];
        __syncthreads();
#pragma unroll 4
        for (int k = 0; k < 64; ++k) {
            const float x0 = Xs[r0 * 128 + kh * 64 + k];
            const float x1 = Xs[(r0 + 1) * 128 + kh * 64 + k];
            const float4 wa = *(const float4*)&Ws[k * 128 + c0];
            const float4 wb = *(const float4*)&Ws[k * 128 + c0 + 4];
            acc[0][0] += x0 * wa.x; acc[0][1] += x0 * wa.y;
            acc[0][2] += x0 * wa.z; acc[0][3] += x0 * wa.w;
            acc[0][4] += x0 * wb.x; acc[0][5] += x0 * wb.y;
            acc[0][6] += x0 * wb.z; acc[0][7] += x0 * wb.w;
            acc[1][0] += x1 * wa.x; acc[1][1] += x1 * wa.y;
            acc[1][2] += x1 * wa.z; acc[1][3] += x1 * wa.w;
            acc[1][4] += x1 * wb.x; acc[1][5] += x1 * wb.y;
            acc[1][6] += x1 * wb.z; acc[1][7] += x1 * wb.w;
        }
    }

#pragma unroll
    for (int r = 0; r < 2; ++r)
#pragma unroll
        for (int c = 0; c < 8; ++c) acc[r][c] = fmaxf(acc[r][c], 0.0f);

    if (!fuse_final) {
#pragma unroll
        for (int r = 0; r < 2; ++r) {
            float4 va = make_float4(acc[r][0], acc[r][1], acc[r][2], acc[r][3]);
            float4 vb = make_float4(acc[r][4], acc[r][5], acc[r][6], acc[r][7]);
            *(float4*)&H[(row0 + r0 + r) * 128 + c0]     = va;
            *(float4*)&H[(row0 + r0 + r) * 128 + c0 + 4] = vb;
        }
    } else {
        float p0 = 0.0f, p1 = 0.0f;
#pragma unroll
        for (int c = 0; c < 8; ++c) {
            p0 += acc[0][c] * w3s[c0 + c];
            p1 += acc[1][c] * w3s[c0 + c];
        }
        // threads sharing a row-pair are 16 consecutive lanes -> xor-shuffle reduce
#pragma unroll
        for (int m = 1; m < 16; m <<= 1) {
            p0 += __shfl_xor(p0, m, 64);
            p1 += __shfl_xor(p1, m, 64);
        }
        if (cg == 0) {
            angles[row0 + r0]     = p0;
            angles[row0 + r0 + 1] = p1;
        }
    }
}

// ---------------------------------------------------------------------------
// Build bitset adjacency: adj[r][c] bit set for every (r,c) edge (dedup by OR).
// ---------------------------------------------------------------------------
__global__ void build_adj(const int* __restrict__ ei, unsigned int* __restrict__ adj)
{
    int e = blockIdx.x * blockDim.x + threadIdx.x;
    if (e < NE) {
        int r = ei[e];
        int c = ei[NE + e];
        atomicOr(&adj[r * WPR + (c >> 5)], 1u << (c & 31));
    }
}

// Hop-1 scatter over the RAW edge list (duplicates counted, per reference).
__global__ void scatter_s1(const int* __restrict__ ei, const float* __restrict__ angles,
                           float* __restrict__ s1)
{
    int e = blockIdx.x * blockDim.x + threadIdx.x;
    if (e < NE) {
        int r = ei[e];
        int c = ei[NE + e];
        atomicAdd(&s1[r], F1 * angles[c]);
    }
}

__global__ void e1_kernel(const float* __restrict__ angles, const float* __restrict__ s1,
                          float* __restrict__ e1)
{
    int i = blockIdx.x * blockDim.x + threadIdx.x;
    if (i < N) e1[i] = angles[i] + s1[i];
}

// ---------------------------------------------------------------------------
// P2 row i = OR of adj rows of i's neighbors (= (adj^2 > 0) row).
// Also t2[i] = P2[i] . e1, then s2[i] = s1[i] + F2*t2, e2[i] = e1[i] + s2[i].
// One block (256 thr) per row; thread t owns u32 word t of the row.
// ---------------------------------------------------------------------------
__global__ __launch_bounds__(256) void p2_kernel(
    const unsigned int* __restrict__ adj, unsigned int* __restrict__ P2,
    const float* __restrict__ e1, const float* __restrict__ s1,
    float* __restrict__ s2, float* __restrict__ e2)
{
    __shared__ int nbr[N];       // worst case a row has N neighbors
    __shared__ int cnt;
    __shared__ float red[256];

    const int i = blockIdx.x;
    const int t = threadIdx.x;
    if (t == 0) cnt = 0;
    __syncthreads();

    // extract neighbor indices from adj row i
    unsigned int aw = adj[i * WPR + t];
    while (aw) {
        int b = __ffs(aw) - 1;
        aw &= aw - 1;
        int p = atomicAdd(&cnt, 1);
        nbr[p] = t * 32 + b;
    }
    __syncthreads();

    const int n = cnt;
    unsigned int w = 0;
    for (int q = 0; q < n; ++q)
        w |= adj[nbr[q] * WPR + t];
    P2[i * WPR + t] = w;

    // dot this word's set bits with e1
    float local = 0.0f;
    unsigned int ww = w;
    const int base = t * 32;
    while (ww) {
        int b = __ffs(ww) - 1;
        ww &= ww - 1;
        local += e1[base + b];
    }
    red[t] = local;
    __syncthreads();
    for (int off = 128; off > 0; off >>= 1) {
        if (t < off) red[t] += red[t + off];
        __syncthreads();
    }
    if (t == 0) {
        float s2v = s1[i] + F2 * red[0];
        s2[i] = s2v;
        e2[i] = e1[i] + s2v;
    }
}

// ---------------------------------------------------------------------------
// P3 row i = OR of P2 rows of i's adj-neighbors ((adj*P2>0) == (adj^3>0) ==
// reference's (P2*adj>0)). Never materialized: built in regs, dotted with e2.
// out[i] = e2[i] + s2[i] + F3 * (P3[i] . e2)
// ---------------------------------------------------------------------------
__global__ __launch_bounds__(256) void p3_kernel(
    const unsigned int* __restrict__ adj, const unsigned int* __restrict__ P2,
    const float* __restrict__ e2, const float* __restrict__ s2,
    float* __restrict__ out)
{
    __shared__ int nbr[N];
    __shared__ int cnt;
    __shared__ float red[256];

    const int i = blockIdx.x;
    const int t = threadIdx.x;
    if (t == 0) cnt = 0;
    __syncthreads();

    unsigned int aw = adj[i * WPR + t];
    while (aw) {
        int b = __ffs(aw) - 1;
        aw &= aw - 1;
        int p = atomicAdd(&cnt, 1);
        nbr[p] = t * 32 + b;
    }
    __syncthreads();

    const int n = cnt;
    unsigned int w = 0;
    for (int q = 0; q < n; ++q)
        w |= P2[nbr[q] * WPR + t];

    float local = 0.0f;
    const int base = t * 32;
    while (w) {
        int b = __ffs(w) - 1;
        w &= w - 1;
        local += e2[base + b];
    }
    red[t] = local;
    __syncthreads();
    for (int off = 128; off > 0; off >>= 1) {
        if (t < off) red[t] += red[t + off];
        __syncthreads();
    }
    if (t == 0)
        out[i] = e2[i] + s2[i] + F3 * red[0];
}

// ---------------------------------------------------------------------------
// Launch
// ---------------------------------------------------------------------------
extern "C" void kernel_launch(void* const* d_in, const int* in_sizes, int n_in,
                              void* d_out, int out_size, void* d_ws, size_t ws_size,
                              hipStream_t stream)
{
    const float* coeffs = (const float*)d_in[0];
    const float* W0     = (const float*)d_in[1];
    const float* W1     = (const float*)d_in[2];
    const float* W2     = (const float*)d_in[3];
    const float* W3     = (const float*)d_in[4];
    const int*   ei     = (const int*)  d_in[5];
    float* out = (float*)d_out;

    char* ws = (char*)d_ws;
    // workspace layout (bytes)
    float*        h0     = (float*)(ws + 0);                 // 4 MB
    float*        h1     = (float*)(ws + (4u << 20));        // 4 MB
    float*        angles = (float*)(ws + (8u << 20));        // 32 KB
    float*        s1     = (float*)(ws + (8u << 20) + 32768);
    float*        e1     = (float*)(ws + (8u << 20) + 2 * 32768);
    float*        s2     = (float*)(ws + (8u << 20) + 3 * 32768);
    float*        e2     = (float*)(ws + (8u << 20) + 4 * 32768);
    unsigned int* adj    = (unsigned int*)(ws + (9u << 20)); // 8 MB
    unsigned int* P2     = (unsigned int*)(ws + (17u << 20));// 8 MB

    // zero the atomically-accumulated buffers (ws is poisoned before each call)
    hipMemsetAsync(adj, 0, (size_t)N * WPR * sizeof(unsigned int), stream);
    hipMemsetAsync(s1, 0, (size_t)N * sizeof(float), stream);

    // MLP (fp32, W3-dot fused into last layer)
    gemm_relu<<<N / 32, 256, 0, stream>>>(coeffs, W0, h0, nullptr, nullptr, 0);
    gemm_relu<<<N / 32, 256, 0, stream>>>(h0, W1, h1, nullptr, nullptr, 0);
    gemm_relu<<<N / 32, 256, 0, stream>>>(h1, W2, nullptr, W3, angles, 1);

    // graph side
    build_adj<<<NE / 256, 256, 0, stream>>>(ei, adj);
    scatter_s1<<<NE / 256, 256, 0, stream>>>(ei, angles, s1);
    e1_kernel<<<N / 256, 256, 0, stream>>>(angles, s1, e1);

    p2_kernel<<<N, 256, 0, stream>>>(adj, P2, e1, s1, s2, e2);
    p3_kernel<<<N, 256, 0, stream>>>(adj, P2, e2, s2, out);
}

// Round 2
// 184.055 us; speedup vs baseline: 1.1571x; 1.1571x over previous
//
#include <hip/hip_runtime.h>

// Problem constants (match reference)
constexpr int N    = 8192;     // nodes
constexpr int D    = 128;      // feature dim
constexpr int NE   = 131072;   // edges
constexpr int WPR  = N / 32;   // 256 u32 words per bitset row
constexpr int MAXD = 128;      // max distinct out-degree supported (actual max ~45)

// f(k) = exp(-ALPHA*k), ALPHA = 2
#define F1 0.13533528323661270f   // e^-2
#define F2 0.018315638888734179f  // e^-4
#define F3 0.0024787521766663585f // e^-6

// ---------------------------------------------------------------------------
// GEMM: H = relu(X @ W), X [N,128], W [128,128].
// If fuse_final: after relu, dot rows with W3 [128] -> angles[N].
// ---------------------------------------------------------------------------
__global__ __launch_bounds__(256) void gemm_relu(
    const float* __restrict__ X, const float* __restrict__ W,
    float* __restrict__ H, const float* __restrict__ W3,
    float* __restrict__ angles, int fuse_final)
{
    __shared__ float Xs[32 * 128];
    __shared__ float Ws[64 * 128];
    __shared__ float w3s[128];

    const int tid  = threadIdx.x;
    const int row0 = blockIdx.x * 32;

    for (int i = tid * 4; i < 32 * 128; i += 256 * 4)
        *(float4*)&Xs[i] = *(const float4*)&X[row0 * 128 + i];
    if (fuse_final && tid < 128) w3s[tid] = W3[tid];

    const int cg = tid & 15;       // 16 col-groups of 8 cols
    const int rp = tid >> 4;       // 16 row-pairs
    const int r0 = rp * 2;
    const int c0 = cg * 8;

    float acc[2][8];
#pragma unroll
    for (int r = 0; r < 2; ++r)
#pragma unroll
        for (int c = 0; c < 8; ++c) acc[r][c] = 0.0f;

    for (int kh = 0; kh < 2; ++kh) {
        __syncthreads();
        for (int i = tid * 4; i < 64 * 128; i += 256 * 4)
            *(float4*)&Ws[i] = *(const float4*)&W[kh * 64 * 128 + i];
        __syncthreads();
#pragma unroll 4
        for (int k = 0; k < 64; ++k) {
            const float x0 = Xs[r0 * 128 + kh * 64 + k];
            const float x1 = Xs[(r0 + 1) * 128 + kh * 64 + k];
            const float4 wa = *(const float4*)&Ws[k * 128 + c0];
            const float4 wb = *(const float4*)&Ws[k * 128 + c0 + 4];
            acc[0][0] += x0 * wa.x; acc[0][1] += x0 * wa.y;
            acc[0][2] += x0 * wa.z; acc[0][3] += x0 * wa.w;
            acc[0][4] += x0 * wb.x; acc[0][5] += x0 * wb.y;
            acc[0][6] += x0 * wb.z; acc[0][7] += x0 * wb.w;
            acc[1][0] += x1 * wa.x; acc[1][1] += x1 * wa.y;
            acc[1][2] += x1 * wa.z; acc[1][3] += x1 * wa.w;
            acc[1][4] += x1 * wb.x; acc[1][5] += x1 * wb.y;
            acc[1][6] += x1 * wb.z; acc[1][7] += x1 * wb.w;
        }
    }

#pragma unroll
    for (int r = 0; r < 2; ++r)
#pragma unroll
        for (int c = 0; c < 8; ++c) acc[r][c] = fmaxf(acc[r][c], 0.0f);

    if (!fuse_final) {
#pragma unroll
        for (int r = 0; r < 2; ++r) {
            float4 va = make_float4(acc[r][0], acc[r][1], acc[r][2], acc[r][3]);
            float4 vb = make_float4(acc[r][4], acc[r][5], acc[r][6], acc[r][7]);
            *(float4*)&H[(row0 + r0 + r) * 128 + c0]     = va;
            *(float4*)&H[(row0 + r0 + r) * 128 + c0 + 4] = vb;
        }
    } else {
        float p0 = 0.0f, p1 = 0.0f;
#pragma unroll
        for (int c = 0; c < 8; ++c) {
            p0 += acc[0][c] * w3s[c0 + c];
            p1 += acc[1][c] * w3s[c0 + c];
        }
#pragma unroll
        for (int m = 1; m < 16; m <<= 1) {
            p0 += __shfl_xor(p0, m, 64);
            p1 += __shfl_xor(p1, m, 64);
        }
        if (cg == 0) {
            angles[row0 + r0]     = p0;
            angles[row0 + r0 + 1] = p1;
        }
    }
}

// ---------------------------------------------------------------------------
// Build bitset adjacency (dedup by OR).
// ---------------------------------------------------------------------------
__global__ void build_adj(const int* __restrict__ ei, unsigned int* __restrict__ adj)
{
    int e = blockIdx.x * blockDim.x + threadIdx.x;
    if (e < NE) {
        int r = ei[e];
        int c = ei[NE + e];
        atomicOr(&adj[r * WPR + (c >> 5)], 1u << (c & 31));
    }
}

// Hop-1 scatter over the RAW edge list (duplicates counted, per reference).
__global__ void scatter_s1(const int* __restrict__ ei, const float* __restrict__ angles,
                           float* __restrict__ s1)
{
    int e = blockIdx.x * blockDim.x + threadIdx.x;
    if (e < NE) {
        int r = ei[e];
        int c = ei[NE + e];
        atomicAdd(&s1[r], F1 * angles[c]);
    }
}

__global__ void e1_kernel(const float* __restrict__ angles, const float* __restrict__ s1,
                          float* __restrict__ e1)
{
    int i = blockIdx.x * blockDim.x + threadIdx.x;
    if (i < N) e1[i] = angles[i] + s1[i];
}

// ---------------------------------------------------------------------------
// P2 row i = OR of adj rows of i's neighbors. Epilogue: s2/e2.
// Also emits the per-row neighbor CSR (count + list) for p3 to reuse.
// LDS ~1 KB -> occupancy wave-capped, not LDS-capped.
// ---------------------------------------------------------------------------
__global__ __launch_bounds__(256) void p2_kernel(
    const unsigned int* __restrict__ adj, unsigned int* __restrict__ P2,
    const float* __restrict__ e1, const float* __restrict__ s1,
    float* __restrict__ s2, float* __restrict__ e2,
    int* __restrict__ cnt_g, int* __restrict__ nbr_g)
{
    __shared__ int nbr[MAXD];
    __shared__ int cnt;
    __shared__ float red[4];

    const int i = blockIdx.x;
    const int t = threadIdx.x;
    if (t == 0) cnt = 0;
    __syncthreads();

    // extract neighbor indices from adj row i (~16 set bits total per row)
    unsigned int aw = adj[i * WPR + t];
    while (aw) {
        int b = __ffs(aw) - 1;
        aw &= aw - 1;
        int p = atomicAdd(&cnt, 1);
        if (p < MAXD) nbr[p] = t * 32 + b;
    }
    __syncthreads();

    const int n = min(cnt, MAXD);
    unsigned int w = 0;
    for (int q = 0; q < n; ++q)
        w |= adj[nbr[q] * WPR + t];
    P2[i * WPR + t] = w;

    // save CSR for p3
    if (t == 0) cnt_g[i] = n;
    if (t < n) nbr_g[i * MAXD + t] = nbr[t];

    // sparse dot (P2 density here ~1 bit / 32-bit word)
    float local = 0.0f;
    unsigned int ww = w;
    const int base = t * 32;
    while (ww) {
        int b = __ffs(ww) - 1;
        ww &= ww - 1;
        local += e1[base + b];
    }
#pragma unroll
    for (int m = 1; m < 64; m <<= 1) local += __shfl_xor(local, m, 64);
    if ((t & 63) == 0) red[t >> 6] = local;
    __syncthreads();
    if (t == 0) {
        float tot = red[0] + red[1] + red[2] + red[3];
        float s2v = s1[i] + F2 * tot;
        s2[i] = s2v;
        e2[i] = e1[i] + s2v;
    }
}

// ---------------------------------------------------------------------------
// P3 row i (never materialized) = OR of P2 rows of i's neighbors.
// out[i] = e2[i] + s2[i] + F3 * (P3[i] . e2)
// P3 rows are ~50% dense -> branch-free cndmask dot (8 independent float4
// loads of L1-resident e2 per thread, no divergent ffs chain).
// ---------------------------------------------------------------------------
__global__ __launch_bounds__(256) void p3_kernel(
    const unsigned int* __restrict__ P2,
    const int* __restrict__ cnt_g, const int* __restrict__ nbr_g,
    const float* __restrict__ e2, const float* __restrict__ s2,
    float* __restrict__ out)
{
    __shared__ int nbr[MAXD];
    __shared__ float red[4];

    const int i = blockIdx.x;
    const int t = threadIdx.x;
    const int n = cnt_g[i];                 // uniform broadcast load
    if (t < n) nbr[t] = nbr_g[i * MAXD + t];
    __syncthreads();

    unsigned int w = 0;
    for (int q = 0; q < n; ++q)
        w |= P2[nbr[q] * WPR + t];

    float local = 0.0f;
    const float4* e4 = (const float4*)(e2 + t * 32);
#pragma unroll
    for (int g = 0; g < 8; ++g) {
        float4 v = e4[g];
        unsigned int m = w >> (g * 4);
        local += (m & 1u) ? v.x : 0.0f;
        local += (m & 2u) ? v.y : 0.0f;
        local += (m & 4u) ? v.z : 0.0f;
        local += (m & 8u) ? v.w : 0.0f;
    }
#pragma unroll
    for (int m = 1; m < 64; m <<= 1) local += __shfl_xor(local, m, 64);
    if ((t & 63) == 0) red[t >> 6] = local;
    __syncthreads();
    if (t == 0)
        out[i] = e2[i] + s2[i] + F3 * (red[0] + red[1] + red[2] + red[3]);
}

// ---------------------------------------------------------------------------
// Launch
// ---------------------------------------------------------------------------
extern "C" void kernel_launch(void* const* d_in, const int* in_sizes, int n_in,
                              void* d_out, int out_size, void* d_ws, size_t ws_size,
                              hipStream_t stream)
{
    const float* coeffs = (const float*)d_in[0];
    const float* W0     = (const float*)d_in[1];
    const float* W1     = (const float*)d_in[2];
    const float* W2     = (const float*)d_in[3];
    const float* W3     = (const float*)d_in[4];
    const int*   ei     = (const int*)  d_in[5];
    float* out = (float*)d_out;

    char* ws = (char*)d_ws;
    // workspace layout (bytes)
    float*        h0     = (float*)(ws + 0);                 // 4 MB
    float*        h1     = (float*)(ws + (4u << 20));        // 4 MB
    float*        angles = (float*)(ws + (8u << 20));        // 32 KB each below
    float*        s1     = (float*)(ws + (8u << 20) + 1 * 32768);
    float*        e1     = (float*)(ws + (8u << 20) + 2 * 32768);
    float*        s2     = (float*)(ws + (8u << 20) + 3 * 32768);
    float*        e2     = (float*)(ws + (8u << 20) + 4 * 32768);
    unsigned int* adj    = (unsigned int*)(ws + (9u << 20)); // 8 MB
    unsigned int* P2     = (unsigned int*)(ws + (17u << 20));// 8 MB
    int*          cnt_g  = (int*)(ws + (25u << 20));         // 32 KB
    int*          nbr_g  = (int*)(ws + (25u << 20) + 32768); // 4 MB

    hipMemsetAsync(adj, 0, (size_t)N * WPR * sizeof(unsigned int), stream);
    hipMemsetAsync(s1, 0, (size_t)N * sizeof(float), stream);

    // MLP (fp32, W3-dot fused into last layer)
    gemm_relu<<<N / 32, 256, 0, stream>>>(coeffs, W0, h0, nullptr, nullptr, 0);
    gemm_relu<<<N / 32, 256, 0, stream>>>(h0, W1, h1, nullptr, nullptr, 0);
    gemm_relu<<<N / 32, 256, 0, stream>>>(h1, W2, nullptr, W3, angles, 1);

    // graph side
    build_adj<<<NE / 256, 256, 0, stream>>>(ei, adj);
    scatter_s1<<<NE / 256, 256, 0, stream>>>(ei, angles, s1);
    e1_kernel<<<N / 256, 256, 0, stream>>>(angles, s1, e1);

    p2_kernel<<<N, 256, 0, stream>>>(adj, P2, e1, s1, s2, e2, cnt_g, nbr_g);
    p3_kernel<<<N, 256, 0, stream>>>(P2, cnt_g, nbr_g, e2, s2, out);
}

// Round 3
// 156.802 us; speedup vs baseline: 1.3582x; 1.1738x over previous
//
#include <hip/hip_runtime.h>

// Problem constants (match reference)
constexpr int N    = 8192;     // nodes
constexpr int NE   = 131072;   // edges
constexpr int WPR  = N / 32;   // 256 u32 words per bitset row
constexpr int MAXD = 64;       // max distinct out-degree (Poisson(16); P(>64) ~ 1e-19)

// f(k) = exp(-ALPHA*k), ALPHA = 2
#define F1 0.13533528323661270f   // e^-2
#define F2 0.018315638888734179f  // e^-4
#define F3 0.0024787521766663585f // e^-6

// ---------------------------------------------------------------------------
// GEMM: H = relu(X @ W), X [N,128], W [128,128].
// If fuse_final: after relu, dot rows with W3 [128] -> angles[N].
// ---------------------------------------------------------------------------
__global__ __launch_bounds__(256) void gemm_relu(
    const float* __restrict__ X, const float* __restrict__ W,
    float* __restrict__ H, const float* __restrict__ W3,
    float* __restrict__ angles, int fuse_final)
{
    __shared__ float Xs[32 * 128];
    __shared__ float Ws[64 * 128];
    __shared__ float w3s[128];

    const int tid  = threadIdx.x;
    const int row0 = blockIdx.x * 32;

    for (int i = tid * 4; i < 32 * 128; i += 256 * 4)
        *(float4*)&Xs[i] = *(const float4*)&X[row0 * 128 + i];
    if (fuse_final && tid < 128) w3s[tid] = W3[tid];

    const int cg = tid & 15;       // 16 col-groups of 8 cols
    const int rp = tid >> 4;       // 16 row-pairs
    const int r0 = rp * 2;
    const int c0 = cg * 8;

    float acc[2][8];
#pragma unroll
    for (int r = 0; r < 2; ++r)
#pragma unroll
        for (int c = 0; c < 8; ++c) acc[r][c] = 0.0f;

    for (int kh = 0; kh < 2; ++kh) {
        __syncthreads();
        for (int i = tid * 4; i < 64 * 128; i += 256 * 4)
            *(float4*)&Ws[i] = *(const float4*)&W[kh * 64 * 128 + i];
        __syncthreads();
#pragma unroll 4
        for (int k = 0; k < 64; ++k) {
            const float x0 = Xs[r0 * 128 + kh * 64 + k];
            const float x1 = Xs[(r0 + 1) * 128 + kh * 64 + k];
            const float4 wa = *(const float4*)&Ws[k * 128 + c0];
            const float4 wb = *(const float4*)&Ws[k * 128 + c0 + 4];
            acc[0][0] += x0 * wa.x; acc[0][1] += x0 * wa.y;
            acc[0][2] += x0 * wa.z; acc[0][3] += x0 * wa.w;
            acc[0][4] += x0 * wb.x; acc[0][5] += x0 * wb.y;
            acc[0][6] += x0 * wb.z; acc[0][7] += x0 * wb.w;
            acc[1][0] += x1 * wa.x; acc[1][1] += x1 * wa.y;
            acc[1][2] += x1 * wa.z; acc[1][3] += x1 * wa.w;
            acc[1][4] += x1 * wb.x; acc[1][5] += x1 * wb.y;
            acc[1][6] += x1 * wb.z; acc[1][7] += x1 * wb.w;
        }
    }

#pragma unroll
    for (int r = 0; r < 2; ++r)
#pragma unroll
        for (int c = 0; c < 8; ++c) acc[r][c] = fmaxf(acc[r][c], 0.0f);

    if (!fuse_final) {
#pragma unroll
        for (int r = 0; r < 2; ++r) {
            float4 va = make_float4(acc[r][0], acc[r][1], acc[r][2], acc[r][3]);
            float4 vb = make_float4(acc[r][4], acc[r][5], acc[r][6], acc[r][7]);
            *(float4*)&H[(row0 + r0 + r) * 128 + c0]     = va;
            *(float4*)&H[(row0 + r0 + r) * 128 + c0 + 4] = vb;
        }
    } else {
        float p0 = 0.0f, p1 = 0.0f;
#pragma unroll
        for (int c = 0; c < 8; ++c) {
            p0 += acc[0][c] * w3s[c0 + c];
            p1 += acc[1][c] * w3s[c0 + c];
        }
#pragma unroll
        for (int m = 1; m < 16; m <<= 1) {
            p0 += __shfl_xor(p0, m, 64);
            p1 += __shfl_xor(p1, m, 64);
        }
        if (cg == 0) {
            angles[row0 + r0]     = p0;
            angles[row0 + r0 + 1] = p1;
        }
    }
}

// ---------------------------------------------------------------------------
// Merged edge pass: bitset adjacency (dedup by OR) + hop-1 scatter over the
// RAW edge list (duplicates counted, per reference).
// ---------------------------------------------------------------------------
__global__ void edges_kernel(const int* __restrict__ ei,
                             const float* __restrict__ angles,
                             unsigned int* __restrict__ adj,
                             float* __restrict__ s1)
{
    int e = blockIdx.x * blockDim.x + threadIdx.x;
    if (e < NE) {
        int r = ei[e];
        int c = ei[NE + e];
        atomicOr(&adj[r * WPR + (c >> 5)], 1u << (c & 31));
        atomicAdd(&s1[r], F1 * angles[c]);
    }
}

__global__ void e1_kernel(const float* __restrict__ angles, const float* __restrict__ s1,
                          float* __restrict__ e1)
{
    int i = blockIdx.x * blockDim.x + threadIdx.x;
    if (i < N) e1[i] = angles[i] + s1[i];
}

// ---------------------------------------------------------------------------
// P2 row i = OR of adj rows of i's neighbors. One WAVE per row, 4 rows/block.
// Lane l owns words {l, 64+l, 128+l, 192+l} (stride-64: all row loads/stores
// are coalesced b32). Epilogue: s2/e2. Emits per-row CSR for p3.
// ---------------------------------------------------------------------------
__global__ __launch_bounds__(256) void p2_kernel(
    const unsigned int* __restrict__ adj, unsigned int* __restrict__ P2,
    const float* __restrict__ e1, const float* __restrict__ s1,
    float* __restrict__ s2, float* __restrict__ e2,
    int* __restrict__ cnt_g, int* __restrict__ nbr_g)
{
    __shared__ int nbr[4][MAXD];
    __shared__ int cnt[4];

    const int wv = threadIdx.x >> 6;
    const int l  = threadIdx.x & 63;
    const int i  = blockIdx.x * 4 + wv;

    if (l == 0) cnt[wv] = 0;
    __syncthreads();

    // extract neighbor ids from adj row i (~16 set bits/row)
    unsigned int a[4];
#pragma unroll
    for (int s = 0; s < 4; ++s) a[s] = adj[(size_t)i * WPR + s * 64 + l];
#pragma unroll
    for (int s = 0; s < 4; ++s) {
        unsigned int aw = a[s];
        const int base = (s * 64 + l) * 32;
        while (aw) {
            int b = __ffs(aw) - 1;
            aw &= aw - 1;
            int p = atomicAdd(&cnt[wv], 1);
            if (p < MAXD) nbr[wv][p] = base + b;
        }
    }
    __syncthreads();

    const int n = min(cnt[wv], MAXD);
    unsigned int w[4] = {0u, 0u, 0u, 0u};
    for (int q = 0; q < n; ++q) {
        const unsigned int* rowp = adj + (size_t)nbr[wv][q] * WPR + l;
#pragma unroll
        for (int s = 0; s < 4; ++s) w[s] |= rowp[s * 64];
    }
#pragma unroll
    for (int s = 0; s < 4; ++s) P2[(size_t)i * WPR + s * 64 + l] = w[s];

    if (l == 0) cnt_g[i] = n;
    if (l < n) nbr_g[i * MAXD + l] = nbr[wv][l];

    // sparse dot: P2 density ~3% -> ffs iterate (~4 bits/lane)
    float local = 0.0f;
#pragma unroll
    for (int s = 0; s < 4; ++s) {
        unsigned int ww = w[s];
        const int base = (s * 64 + l) * 32;
        while (ww) {
            int b = __ffs(ww) - 1;
            ww &= ww - 1;
            local += e1[base + b];
        }
    }
#pragma unroll
    for (int m = 1; m < 64; m <<= 1) local += __shfl_xor(local, m, 64);
    if (l == 0) {
        float s2v = s1[i] + F2 * local;
        s2[i] = s2v;
        e2[i] = e1[i] + s2v;
    }
}

// ---------------------------------------------------------------------------
// P3 row i (never materialized) = OR of P2 rows of i's neighbors.
// out[i] = e2[i] + s2[i] + F3 * (P3[i] . e2)
// One wave per row. Dense dot (P3 ~50% dense): 32 chunks; lane l reads
// float4 e2[c*256 + 4l] (coalesced 1KB/instr); the 4-bit mask for those
// floats lives in word c*8 + (l>>3), register slot c>>3 (uniform) of owner
// lane (c&7)*8 + (l>>3) -> one __shfl per chunk.
// ---------------------------------------------------------------------------
__global__ __launch_bounds__(256) void p3_kernel(
    const unsigned int* __restrict__ P2,
    const int* __restrict__ cnt_g, const int* __restrict__ nbr_g,
    const float* __restrict__ e2, const float* __restrict__ s2,
    float* __restrict__ out)
{
    __shared__ int nbr[4][MAXD];

    const int wv = threadIdx.x >> 6;
    const int l  = threadIdx.x & 63;
    const int i  = blockIdx.x * 4 + wv;

    const int n = cnt_g[i];
    if (l < n) nbr[wv][l] = nbr_g[i * MAXD + l];
    __syncthreads();

    unsigned int w[4] = {0u, 0u, 0u, 0u};
    for (int q = 0; q < n; ++q) {
        const unsigned int* rowp = P2 + (size_t)nbr[wv][q] * WPR + l;
#pragma unroll
        for (int s = 0; s < 4; ++s) w[s] |= rowp[s * 64];
    }

    float local = 0.0f;
#pragma unroll
    for (int c = 0; c < 32; ++c) {
        unsigned int wd  = __shfl(w[c >> 3], ((c & 7) << 3) | (l >> 3), 64);
        unsigned int nib = wd >> ((l & 7) * 4);
        float4 v = *(const float4*)&e2[c * 256 + l * 4];
        local += (nib & 1u) ? v.x : 0.0f;
        local += (nib & 2u) ? v.y : 0.0f;
        local += (nib & 4u) ? v.z : 0.0f;
        local += (nib & 8u) ? v.w : 0.0f;
    }
#pragma unroll
    for (int m = 1; m < 64; m <<= 1) local += __shfl_xor(local, m, 64);
    if (l == 0)
        out[i] = e2[i] + s2[i] + F3 * local;
}

// ---------------------------------------------------------------------------
// Launch
// ---------------------------------------------------------------------------
extern "C" void kernel_launch(void* const* d_in, const int* in_sizes, int n_in,
                              void* d_out, int out_size, void* d_ws, size_t ws_size,
                              hipStream_t stream)
{
    const float* coeffs = (const float*)d_in[0];
    const float* W0     = (const float*)d_in[1];
    const float* W1     = (const float*)d_in[2];
    const float* W2     = (const float*)d_in[3];
    const float* W3     = (const float*)d_in[4];
    const int*   ei     = (const int*)  d_in[5];
    float* out = (float*)d_out;

    char* ws = (char*)d_ws;
    // workspace layout (bytes)
    float*        h0     = (float*)(ws + 0);                    // 4 MB
    float*        h1     = (float*)(ws + (4u  << 20));          // 4 MB
    float*        angles = (float*)(ws + (8u  << 20));          // 32 KB
    float*        e1     = (float*)(ws + (8u  << 20) + 1 * 32768);
    float*        s2     = (float*)(ws + (8u  << 20) + 2 * 32768);
    float*        e2     = (float*)(ws + (8u  << 20) + 3 * 32768);
    int*          cnt_g  = (int*)  (ws + (8u  << 20) + 4 * 32768);
    int*          nbr_g  = (int*)  (ws + (9u  << 20));          // 2 MB (8192*64*4)
    unsigned int* adj    = (unsigned int*)(ws + (12u << 20));   // 8 MB
    float*        s1     = (float*)(ws + (20u << 20));          // 32 KB, right after adj
    unsigned int* P2     = (unsigned int*)(ws + (24u << 20));   // 8 MB

    // one memset covers adj (8 MB) + s1 (32 KB), laid out contiguously
    hipMemsetAsync(adj, 0, ((size_t)N * WPR) * sizeof(unsigned int) + N * sizeof(float), stream);

    // MLP (fp32, W3-dot fused into last layer)
    gemm_relu<<<N / 32, 256, 0, stream>>>(coeffs, W0, h0, nullptr, nullptr, 0);
    gemm_relu<<<N / 32, 256, 0, stream>>>(h0, W1, h1, nullptr, nullptr, 0);
    gemm_relu<<<N / 32, 256, 0, stream>>>(h1, W2, nullptr, W3, angles, 1);

    // graph side
    edges_kernel<<<NE / 256, 256, 0, stream>>>(ei, angles, adj, s1);
    e1_kernel<<<N / 256, 256, 0, stream>>>(angles, s1, e1);

    p2_kernel<<<N / 4, 256, 0, stream>>>(adj, P2, e1, s1, s2, e2, cnt_g, nbr_g);
    p3_kernel<<<N / 4, 256, 0, stream>>>(P2, cnt_g, nbr_g, e2, s2, out);
}

// Round 4
// 148.873 us; speedup vs baseline: 1.4305x; 1.0533x over previous
//
#include <hip/hip_runtime.h>

// Problem constants (match reference)
constexpr int N    = 8192;     // nodes
constexpr int NE   = 131072;   // edges
constexpr int WPR  = N / 32;   // 256 u32 words per bitset row
constexpr int MAXD = 64;       // max distinct out-degree (Poisson(16); P(>64) ~ 1e-19)

// f(k) = exp(-ALPHA*k), ALPHA = 2
#define F1 0.13533528323661270f   // e^-2
#define F2 0.018315638888734179f  // e^-4
#define F3 0.0024787521766663585f // e^-6

// ---------------------------------------------------------------------------
// Fused MLP: angles = relu(relu(relu(X@W0)@W1)@W2) @ W3, all in one kernel.
// One block = 32 rows, 256 threads, thread = 2 rows x 8 cols.
// LDS: Xs 16 KB (raw, conflict-broken by per-rp k-rotation) +
//      Ws 48 KB (64-row half, float4-pair cg stored at word 12*cg:
//      chunk-slot = 3*cg mod 8 covers all 8 bank groups -> 2-way = free).
// Total 65536 B. W staged in two 64-row halves per layer.
// ---------------------------------------------------------------------------
__global__ __launch_bounds__(256) void mlp_kernel(
    const float* __restrict__ X,
    const float* __restrict__ W0, const float* __restrict__ W1,
    const float* __restrict__ W2, const float* __restrict__ W3,
    float* __restrict__ angles)
{
    __shared__ float Xs[32 * 128];   // 16384 B
    __shared__ float Ws[64 * 192];   // 49152 B (swizzled half of W)

    const int tid  = threadIdx.x;
    const int row0 = blockIdx.x * 32;
    const int cg   = tid & 15;       // col-group (8 cols)
    const int rp   = tid >> 4;       // row-pair id, 0..15
    const int r0   = rp * 2;
    const int c0   = cg * 8;
    const int rot  = (rp & 3) * 4;   // per-wave k rotation: x broadcast addrs
                                     // land in 4 distinct banks, no padding

    // stage coeffs tile (32 rows x 128)
    for (int i = tid * 4; i < 32 * 128; i += 1024)
        *(float4*)&Xs[i] = *(const float4*)&X[row0 * 128 + i];

    float acc[2][8];
    for (int layer = 0; layer < 3; ++layer) {
        const float* __restrict__ W = (layer == 0) ? W0 : (layer == 1) ? W1 : W2;

#pragma unroll
        for (int r = 0; r < 2; ++r)
#pragma unroll
            for (int c = 0; c < 8; ++c) acc[r][c] = 0.0f;

        for (int kh = 0; kh < 2; ++kh) {
            __syncthreads();   // prev compute / Xs writes done before restage
            // stage 64 rows of W, swizzled: chunk j of row k -> word
            // k*192 + (j>>1)*12 + (j&1)*4
#pragma unroll
            for (int it = 0; it < 8; ++it) {
                int q = tid + it * 256;        // 0..2047 float4 chunks
                int k = q >> 5;                // row within half
                int j = q & 31;                // float4 chunk within row
                float4 v = *(const float4*)&W[(kh * 64 + k) * 128 + j * 4];
                *(float4*)&Ws[k * 192 + (j >> 1) * 12 + (j & 1) * 4] = v;
            }
            __syncthreads();

#pragma unroll 8
            for (int k = 0; k < 64; ++k) {
                const int kk = (k + rot) & 63;
                const float x0 = Xs[r0 * 128 + kh * 64 + kk];
                const float x1 = Xs[(r0 + 1) * 128 + kh * 64 + kk];
                const float4 wa = *(const float4*)&Ws[kk * 192 + cg * 12];
                const float4 wb = *(const float4*)&Ws[kk * 192 + cg * 12 + 4];
                acc[0][0] += x0 * wa.x; acc[0][1] += x0 * wa.y;
                acc[0][2] += x0 * wa.z; acc[0][3] += x0 * wa.w;
                acc[0][4] += x0 * wb.x; acc[0][5] += x0 * wb.y;
                acc[0][6] += x0 * wb.z; acc[0][7] += x0 * wb.w;
                acc[1][0] += x1 * wa.x; acc[1][1] += x1 * wa.y;
                acc[1][2] += x1 * wa.z; acc[1][3] += x1 * wa.w;
                acc[1][4] += x1 * wb.x; acc[1][5] += x1 * wb.y;
                acc[1][6] += x1 * wb.z; acc[1][7] += x1 * wb.w;
            }
        }

#pragma unroll
        for (int r = 0; r < 2; ++r)
#pragma unroll
            for (int c = 0; c < 8; ++c) acc[r][c] = fmaxf(acc[r][c], 0.0f);

        __syncthreads();   // everyone done reading Xs before overwrite

        if (layer < 2) {
            // write h back into Xs (it is next layer's X)
#pragma unroll
            for (int r = 0; r < 2; ++r) {
                *(float4*)&Xs[(r0 + r) * 128 + c0] =
                    make_float4(acc[r][0], acc[r][1], acc[r][2], acc[r][3]);
                *(float4*)&Xs[(r0 + r) * 128 + c0 + 4] =
                    make_float4(acc[r][4], acc[r][5], acc[r][6], acc[r][7]);
            }
        } else {
            // final dot with W3 (read direct from global, L2-hot broadcast)
            const float4 w3a = *(const float4*)&W3[c0];
            const float4 w3b = *(const float4*)&W3[c0 + 4];
            float p0 = acc[0][0] * w3a.x + acc[0][1] * w3a.y + acc[0][2] * w3a.z +
                       acc[0][3] * w3a.w + acc[0][4] * w3b.x + acc[0][5] * w3b.y +
                       acc[0][6] * w3b.z + acc[0][7] * w3b.w;
            float p1 = acc[1][0] * w3a.x + acc[1][1] * w3a.y + acc[1][2] * w3a.z +
                       acc[1][3] * w3a.w + acc[1][4] * w3b.x + acc[1][5] * w3b.y +
                       acc[1][6] * w3b.z + acc[1][7] * w3b.w;
#pragma unroll
            for (int m = 1; m < 16; m <<= 1) {
                p0 += __shfl_xor(p0, m, 64);
                p1 += __shfl_xor(p1, m, 64);
            }
            if (cg == 0) {
                angles[row0 + r0]     = p0;
                angles[row0 + r0 + 1] = p1;
            }
        }
    }
}

// ---------------------------------------------------------------------------
// Merged edge pass: bitset adjacency (dedup by OR) + hop-1 scatter over the
// RAW edge list (duplicates counted, per reference).
// ---------------------------------------------------------------------------
__global__ void edges_kernel(const int* __restrict__ ei,
                             const float* __restrict__ angles,
                             unsigned int* __restrict__ adj,
                             float* __restrict__ s1)
{
    int e = blockIdx.x * blockDim.x + threadIdx.x;
    if (e < NE) {
        int r = ei[e];
        int c = ei[NE + e];
        atomicOr(&adj[r * WPR + (c >> 5)], 1u << (c & 31));
        atomicAdd(&s1[r], F1 * angles[c]);
    }
}

// ---------------------------------------------------------------------------
// P2 row i = OR of adj rows of i's neighbors. One WAVE per row, 4 rows/block.
// Lane l owns words {l, 64+l, 128+l, 192+l} (stride-64 -> coalesced b32).
// e1 is never materialized: gathered as angles[j]+s1[j] on the fly.
// Epilogue: s2/e2. Emits per-row CSR for p3.
// ---------------------------------------------------------------------------
__global__ __launch_bounds__(256) void p2_kernel(
    const unsigned int* __restrict__ adj, unsigned int* __restrict__ P2,
    const float* __restrict__ angles, const float* __restrict__ s1,
    float* __restrict__ s2, float* __restrict__ e2,
    int* __restrict__ cnt_g, int* __restrict__ nbr_g)
{
    __shared__ int nbr[4][MAXD];
    __shared__ int cnt[4];

    const int wv = threadIdx.x >> 6;
    const int l  = threadIdx.x & 63;
    const int i  = blockIdx.x * 4 + wv;

    if (l == 0) cnt[wv] = 0;
    __syncthreads();

    // extract neighbor ids from adj row i (~16 set bits/row)
    unsigned int a[4];
#pragma unroll
    for (int s = 0; s < 4; ++s) a[s] = adj[(size_t)i * WPR + s * 64 + l];
#pragma unroll
    for (int s = 0; s < 4; ++s) {
        unsigned int aw = a[s];
        const int base = (s * 64 + l) * 32;
        while (aw) {
            int b = __ffs(aw) - 1;
            aw &= aw - 1;
            int p = atomicAdd(&cnt[wv], 1);
            if (p < MAXD) nbr[wv][p] = base + b;
        }
    }
    __syncthreads();

    const int n = min(cnt[wv], MAXD);
    unsigned int w[4] = {0u, 0u, 0u, 0u};
    for (int q = 0; q < n; ++q) {
        const unsigned int* rowp = adj + (size_t)nbr[wv][q] * WPR + l;
#pragma unroll
        for (int s = 0; s < 4; ++s) w[s] |= rowp[s * 64];
    }
#pragma unroll
    for (int s = 0; s < 4; ++s) P2[(size_t)i * WPR + s * 64 + l] = w[s];

    if (l == 0) cnt_g[i] = n;
    if (l < n) nbr_g[i * MAXD + l] = nbr[wv][l];

    // sparse dot: P2 density ~3% -> ffs iterate (~4 bits/lane)
    float local = 0.0f;
#pragma unroll
    for (int s = 0; s < 4; ++s) {
        unsigned int ww = w[s];
        const int base = (s * 64 + l) * 32;
        while (ww) {
            int b = __ffs(ww) - 1;
            ww &= ww - 1;
            local += angles[base + b] + s1[base + b];
        }
    }
#pragma unroll
    for (int m = 1; m < 64; m <<= 1) local += __shfl_xor(local, m, 64);
    if (l == 0) {
        float e1i = angles[i] + s1[i];
        float s2v = s1[i] + F2 * local;
        s2[i] = s2v;
        e2[i] = e1i + s2v;
    }
}

// ---------------------------------------------------------------------------
// P3 row i (never materialized) = OR of P2 rows of i's neighbors.
// out[i] = e2[i] + s2[i] + F3 * (P3[i] . e2)
// One wave per row. Dense dot (P3 ~50% dense): 32 chunks; lane l reads
// float4 e2[c*256 + 4l] (coalesced 1KB/instr); mask nibble fetched from the
// owning lane with one __shfl per chunk (register slot c>>3 is uniform).
// ---------------------------------------------------------------------------
__global__ __launch_bounds__(256) void p3_kernel(
    const unsigned int* __restrict__ P2,
    const int* __restrict__ cnt_g, const int* __restrict__ nbr_g,
    const float* __restrict__ e2, const float* __restrict__ s2,
    float* __restrict__ out)
{
    __shared__ int nbr[4][MAXD];

    const int wv = threadIdx.x >> 6;
    const int l  = threadIdx.x & 63;
    const int i  = blockIdx.x * 4 + wv;

    const int n = cnt_g[i];
    if (l < n) nbr[wv][l] = nbr_g[i * MAXD + l];
    __syncthreads();

    unsigned int w[4] = {0u, 0u, 0u, 0u};
    for (int q = 0; q < n; ++q) {
        const unsigned int* rowp = P2 + (size_t)nbr[wv][q] * WPR + l;
#pragma unroll
        for (int s = 0; s < 4; ++s) w[s] |= rowp[s * 64];
    }

    float local = 0.0f;
#pragma unroll
    for (int c = 0; c < 32; ++c) {
        unsigned int wd  = __shfl(w[c >> 3], ((c & 7) << 3) | (l >> 3), 64);
        unsigned int nib = wd >> ((l & 7) * 4);
        float4 v = *(const float4*)&e2[c * 256 + l * 4];
        local += (nib & 1u) ? v.x : 0.0f;
        local += (nib & 2u) ? v.y : 0.0f;
        local += (nib & 4u) ? v.z : 0.0f;
        local += (nib & 8u) ? v.w : 0.0f;
    }
#pragma unroll
    for (int m = 1; m < 64; m <<= 1) local += __shfl_xor(local, m, 64);
    if (l == 0)
        out[i] = e2[i] + s2[i] + F3 * local;
}

// ---------------------------------------------------------------------------
// Launch
// ---------------------------------------------------------------------------
extern "C" void kernel_launch(void* const* d_in, const int* in_sizes, int n_in,
                              void* d_out, int out_size, void* d_ws, size_t ws_size,
                              hipStream_t stream)
{
    const float* coeffs = (const float*)d_in[0];
    const float* W0     = (const float*)d_in[1];
    const float* W1     = (const float*)d_in[2];
    const float* W2     = (const float*)d_in[3];
    const float* W3     = (const float*)d_in[4];
    const int*   ei     = (const int*)  d_in[5];
    float* out = (float*)d_out;

    char* ws = (char*)d_ws;
    // workspace layout (bytes)
    float*        angles = (float*)(ws + 0 * 32768);
    float*        s2     = (float*)(ws + 1 * 32768);
    float*        e2     = (float*)(ws + 2 * 32768);
    int*          cnt_g  = (int*)  (ws + 3 * 32768);
    int*          nbr_g  = (int*)  (ws + 4 * 32768);           // 2 MB
    unsigned int* adj    = (unsigned int*)(ws + (4u  << 20));  // 8 MB
    float*        s1     = (float*)(ws + (12u << 20));         // 32 KB, after adj
    unsigned int* P2     = (unsigned int*)(ws + (13u << 20));  // 8 MB

    // one memset covers adj (8 MB) + s1 (32 KB), laid out contiguously
    hipMemsetAsync(adj, 0, ((size_t)N * WPR) * sizeof(unsigned int) + N * sizeof(float), stream);

    // MLP: single fused kernel
    mlp_kernel<<<N / 32, 256, 0, stream>>>(coeffs, W0, W1, W2, W3, angles);

    // graph side
    edges_kernel<<<NE / 256, 256, 0, stream>>>(ei, angles, adj, s1);
    p2_kernel<<<N / 4, 256, 0, stream>>>(adj, P2, angles, s1, s2, e2, cnt_g, nbr_g);
    p3_kernel<<<N / 4, 256, 0, stream>>>(P2, cnt_g, nbr_g, e2, s2, out);
}